// Round 11
// baseline (129.508 us; speedup 1.0000x reference)
//
#include <hip/hip_runtime.h>
#include <math.h>

constexpr int Nn = 16384;
constexpr int ST = 68;                      // ws row stride (dwords): 64 qk + 4 pp
constexpr size_t NS = (size_t)Nn * 16;      // dwords per channel plane of npts
constexpr int GPB = 8;                      // point-groups (of 16) per persistent block

// ---- DPP helpers ----
template <int CTRL>
__device__ __forceinline__ float dpp_f(float x) {
    return __int_as_float(
        __builtin_amdgcn_update_dpp(0, __float_as_int(x), CTRL, 0xF, 0xF, false));
}
// quad (4-lane) butterflies: quad_perm [1,0,3,2]=0xB1, [2,3,0,1]=0x4E
__device__ __forceinline__ float qsum4(float v) {
    v += dpp_f<0xB1>(v);
    v += dpp_f<0x4E>(v);
    return v;
}
__device__ __forceinline__ float qmax4(float v) {
    v = fmaxf(v, dpp_f<0xB1>(v));
    v = fmaxf(v, dpp_f<0x4E>(v));
    return v;
}

// barrier that does NOT drain vmcnt: LDS-visibility only (T3/T4 essence).
// Global prefetch loads stay in flight across it.
#define BAR() do { asm volatile("s_waitcnt lgkmcnt(0)" ::: "memory"); \
    __builtin_amdgcn_s_barrier(); asm volatile("" ::: "memory"); } while (0)

// ================= Kernel A: qk = Wk^T (q*scale), pp = Wp^T qk =================
// thread = (point, 16-channel quarter); no LDS. (unchanged)
__global__ __launch_bounds__(256, 4) void qkpp_kernel(
    const float* __restrict__ points, const float* __restrict__ Wk,
    const float* __restrict__ Wp, float* __restrict__ ws)
{
    const int tid = threadIdx.x;
    const int lane = tid & 63;
    const int q = lane >> 4;                            // quarter 0..3
    const int pt = blockIdx.x * 64 + (tid >> 6) * 16 + (lane & 15);
    const int b = pt >> 14;
    const int n = pt & (Nn - 1);

    float qk[16];
#pragma unroll
    for (int k = 0; k < 16; ++k) qk[k] = 0.f;

    const float* prow = points + (size_t)b * 64 * Nn + n;
    const float* wkq = Wk + 16 * q;
#pragma unroll 4
    for (int c = 0; c < 64; ++c) {
        const float qv = prow[(size_t)c * Nn];
        const float4 w0 = *(const float4*)(wkq + c * 64 + 0);
        const float4 w1 = *(const float4*)(wkq + c * 64 + 4);
        const float4 w2 = *(const float4*)(wkq + c * 64 + 8);
        const float4 w3 = *(const float4*)(wkq + c * 64 + 12);
        qk[0]  = fmaf(qv, w0.x, qk[0]);  qk[1]  = fmaf(qv, w0.y, qk[1]);
        qk[2]  = fmaf(qv, w0.z, qk[2]);  qk[3]  = fmaf(qv, w0.w, qk[3]);
        qk[4]  = fmaf(qv, w1.x, qk[4]);  qk[5]  = fmaf(qv, w1.y, qk[5]);
        qk[6]  = fmaf(qv, w1.z, qk[6]);  qk[7]  = fmaf(qv, w1.w, qk[7]);
        qk[8]  = fmaf(qv, w2.x, qk[8]);  qk[9]  = fmaf(qv, w2.y, qk[9]);
        qk[10] = fmaf(qv, w2.z, qk[10]); qk[11] = fmaf(qv, w2.w, qk[11]);
        qk[12] = fmaf(qv, w3.x, qk[12]); qk[13] = fmaf(qv, w3.y, qk[13]);
        qk[14] = fmaf(qv, w3.z, qk[14]); qk[15] = fmaf(qv, w3.w, qk[15]);
    }
#pragma unroll
    for (int k = 0; k < 16; ++k) qk[k] *= 0.125f;       // fold SCALE

    float p0 = 0.f, p1 = 0.f, p2 = 0.f, p3 = 0.f;
#pragma unroll
    for (int k = 0; k < 16; ++k) {
        const float4 wp4 = *(const float4*)(Wp + (16 * q + k) * 4);
        p0 = fmaf(qk[k], wp4.x, p0);
        p1 = fmaf(qk[k], wp4.y, p1);
        p2 = fmaf(qk[k], wp4.z, p2);
        p3 = fmaf(qk[k], wp4.w, p3);
    }
    p0 += __shfl_xor(p0, 16); p0 += __shfl_xor(p0, 32);
    p1 += __shfl_xor(p1, 16); p1 += __shfl_xor(p1, 32);
    p2 += __shfl_xor(p2, 16); p2 += __shfl_xor(p2, 32);
    p3 += __shfl_xor(p3, 16); p3 += __shfl_xor(p3, 32);

    float* orow = ws + (size_t)pt * ST + 16 * q;
    ((float4*)orow)[0] = make_float4(qk[0],  qk[1],  qk[2],  qk[3]);
    ((float4*)orow)[1] = make_float4(qk[4],  qk[5],  qk[6],  qk[7]);
    ((float4*)orow)[2] = make_float4(qk[8],  qk[9],  qk[10], qk[11]);
    ((float4*)orow)[3] = make_float4(qk[12], qk[13], qk[14], qk[15]);
    if (q == 0)
        *(float4*)(ws + (size_t)pt * ST + 64) = make_float4(p0, p1, p2, p3);
}

// ====== Kernel B: persistent double-buffered streamer ======
// 512 blocks (2/CU resident). Block owns 128 consecutive points = 8 groups of 16.
// wave w owns channels 16w..16w+15; lane l: point p=l>>2, s-quad sq=l&3.
// Next group's loads are issued BEFORE the current group's compute; barriers
// never drain vmcnt -> memory pipe continuously fed.
__global__ __launch_bounds__(256, 2) void attn_out_kernel(
    const float* __restrict__ xyz, const float* __restrict__ nxyz,
    const float* __restrict__ npts, const float* __restrict__ Wv,
    const float* __restrict__ ws, float* __restrict__ out)
{
    __shared__ float wvT[67 * 68];                     // [c][o], stride 68
    __shared__ __align__(16) float lexch[4][64][4];    // partial-logit exchange
    __shared__ float vbexch[67 * 17];                  // vbar exchange, stride 17

    const int tid = threadIdx.x;
    const int w = tid >> 6;
    const int l = tid & 63;
    const int p = l >> 2;
    const int sq = l & 3;

    const int gptbase = blockIdx.x * (16 * GPB);       // 128-pt chunk, never straddles b
    const int b = gptbase >> 14;
    const int ngbase = gptbase & (Nn - 1);

    // one-time Wv transpose stage (visibility ensured by first in-loop BAR pair)
    for (int idx = tid; idx < 64 * 67; idx += 256) {
        const int o = idx / 67, c = idx - o * 67;
        wvT[c * 68 + o] = Wv[idx];
    }

    const float* npb0 = npts + ((size_t)(b * 64 + 16 * w)) * NS + (size_t)ngbase * 16 + 4 * l;

    float4 npA[16], npB[16], qqA[4], qqB[4], nxA[3], nxB[3];
    float4 ppA = make_float4(0,0,0,0), ppB = make_float4(0,0,0,0);
    float xA[3] = {0,0,0}, xB[3] = {0,0,0};

    auto prefetch = [&](int g, float4 (&np)[16], float4 (&qq)[4],
                        float4 (&nx)[3], float (&xx)[3], float4& pp) {
        const float* npb = npb0 + (size_t)g * 256;     // 16 pts x 16 s dwords / group
#pragma unroll
        for (int k = 0; k < 16; ++k) np[k] = *(const float4*)(npb + (size_t)k * NS);
        const float* qrow = ws + (size_t)(gptbase + 16 * g + p) * ST + 16 * w;
        qq[0] = ((const float4*)qrow)[0];
        qq[1] = ((const float4*)qrow)[1];
        qq[2] = ((const float4*)qrow)[2];
        qq[3] = ((const float4*)qrow)[3];
        if (w == 3) {
            const int ng = ngbase + 16 * g;
            nx[0] = *(const float4*)(nxyz + ((size_t)(b * 3 + 0) * Nn + ng) * 16 + 4 * l);
            nx[1] = *(const float4*)(nxyz + ((size_t)(b * 3 + 1) * Nn + ng) * 16 + 4 * l);
            nx[2] = *(const float4*)(nxyz + ((size_t)(b * 3 + 2) * Nn + ng) * 16 + 4 * l);
            xx[0] = xyz[(size_t)(b * 3 + 0) * Nn + ng + p];
            xx[1] = xyz[(size_t)(b * 3 + 1) * Nn + ng + p];
            xx[2] = xyz[(size_t)(b * 3 + 2) * Nn + ng + p];
            pp = *(const float4*)(ws + (size_t)(gptbase + 16 * g + p) * ST + 64);
        }
    };

    auto step = [&](int g, float4 (&np)[16], float4 (&qq)[4],
                    float4 (&nx)[3], float (&xx)[3], float4& pp) {
        const int ng = ngbase + 16 * g;

        float4 d04 = make_float4(0,0,0,0), d14 = d04, d24 = d04, dn4 = d04;
        if (w == 3) {
            d04 = make_float4(xx[0] - nx[0].x, xx[0] - nx[0].y, xx[0] - nx[0].z, xx[0] - nx[0].w);
            d14 = make_float4(xx[1] - nx[1].x, xx[1] - nx[1].y, xx[1] - nx[1].z, xx[1] - nx[1].w);
            d24 = make_float4(xx[2] - nx[2].x, xx[2] - nx[2].y, xx[2] - nx[2].z, xx[2] - nx[2].w);
            dn4 = make_float4(sqrtf(d04.x * d04.x + d14.x * d14.x + d24.x * d24.x),
                              sqrtf(d04.y * d04.y + d14.y * d14.y + d24.y * d24.y),
                              sqrtf(d04.z * d04.z + d14.z * d14.z + d24.z * d24.z),
                              sqrtf(d04.w * d04.w + d14.w * d14.w + d24.w * d24.w));
        }

        const float qks[16] = {qq[0].x, qq[0].y, qq[0].z, qq[0].w,
                               qq[1].x, qq[1].y, qq[1].z, qq[1].w,
                               qq[2].x, qq[2].y, qq[2].z, qq[2].w,
                               qq[3].x, qq[3].y, qq[3].z, qq[3].w};
        float4 lp = make_float4(0.f, 0.f, 0.f, 0.f);
#pragma unroll
        for (int k = 0; k < 16; ++k) {
            lp.x = fmaf(qks[k], np[k].x, lp.x);
            lp.y = fmaf(qks[k], np[k].y, lp.y);
            lp.z = fmaf(qks[k], np[k].z, lp.z);
            lp.w = fmaf(qks[k], np[k].w, lp.w);
        }
        if (w == 3) {   // + pp . pos  (bp const in s -> cancels in softmax)
            lp.x += pp.x * d04.x + pp.y * d14.x + pp.z * d24.x + pp.w * dn4.x;
            lp.y += pp.x * d04.y + pp.y * d14.y + pp.z * d24.y + pp.w * dn4.y;
            lp.z += pp.x * d04.z + pp.y * d14.z + pp.z * d24.z + pp.w * dn4.z;
            lp.w += pp.x * d04.w + pp.y * d14.w + pp.z * d24.w + pp.w * dn4.w;
        }

        BAR();                                  // WAR: prev group's LDS reads done
        *(float4*)&lexch[w][l][0] = lp;
        BAR();                                  // lexch visible
        const float4 g0 = *(const float4*)&lexch[0][l][0];
        const float4 g1 = *(const float4*)&lexch[1][l][0];
        const float4 g2 = *(const float4*)&lexch[2][l][0];
        const float4 g3 = *(const float4*)&lexch[3][l][0];
        const float4 lg = make_float4(g0.x + g1.x + g2.x + g3.x,
                                      g0.y + g1.y + g2.y + g3.y,
                                      g0.z + g1.z + g2.z + g3.z,
                                      g0.w + g1.w + g2.w + g3.w);

        float mx = fmaxf(fmaxf(lg.x, lg.y), fmaxf(lg.z, lg.w));
        mx = qmax4(mx);
        const float e0 = __expf(lg.x - mx), e1 = __expf(lg.y - mx);
        const float e2 = __expf(lg.z - mx), e3 = __expf(lg.w - mx);
        const float se = qsum4((e0 + e1) + (e2 + e3));
        const float inv = 1.0f / se;
        const float at0 = e0 * inv, at1 = e1 * inv, at2 = e2 * inv, at3 = e3 * inv;

#pragma unroll
        for (int k = 0; k < 16; ++k) {
            float v = at0 * np[k].x + at1 * np[k].y + at2 * np[k].z + at3 * np[k].w;
            v = qsum4(v);                       // vbar[16w+k][p] in all 4 quad lanes
            if (sq == (k & 3)) vbexch[(16 * w + k) * 17 + p] = v;
        }
        if (w == 3) {                           // tail channels 64..66 (= tmp)
            const float t0 = qsum4(at0 * d04.x + at1 * d04.y + at2 * d04.z + at3 * d04.w);
            const float t1 = qsum4(at0 * d14.x + at1 * d14.y + at2 * d14.z + at3 * d14.w);
            const float t2 = qsum4(at0 * d24.x + at1 * d24.y + at2 * d24.z + at3 * d24.w);
            if (sq == 0) vbexch[64 * 17 + p] = t0;
            else if (sq == 1) vbexch[65 * 17 + p] = t1;
            else if (sq == 2) vbexch[66 * 17 + p] = t2;
        }
        BAR();                                  // vbexch visible

        float4 oa = make_float4(0.f, 0.f, 0.f, 0.f);
#pragma unroll
        for (int c = 0; c < 67; ++c) {
            const float vb = vbexch[c * 17 + p];
            const float4 wq = *(const float4*)&wvT[c * 68 + 16 * w + 4 * sq];
            oa.x = fmaf(vb, wq.x, oa.x);
            oa.y = fmaf(vb, wq.y, oa.y);
            oa.z = fmaf(vb, wq.z, oa.z);
            oa.w = fmaf(vb, wq.w, oa.w);
        }

        float* ob = out + ((size_t)(b * 64 + 16 * w + 4 * sq)) * Nn + ng + p;
        ob[0]              = oa.x;
        ob[(size_t)Nn]     = oa.y;
        ob[(size_t)Nn * 2] = oa.z;
        ob[(size_t)Nn * 3] = oa.w;
    };

    prefetch(0, npA, qqA, nxA, xA, ppA);
#pragma unroll 1
    for (int gg = 0; gg < GPB / 2; ++gg) {
        prefetch(2 * gg + 1, npB, qqB, nxB, xB, ppB);   // issue next loads FIRST
        step(2 * gg, npA, qqA, nxA, xA, ppA);           // compute current
        if (2 * gg + 2 < GPB)
            prefetch(2 * gg + 2, npA, qqA, nxA, xA, ppA);
        step(2 * gg + 1, npB, qqB, nxB, xB, ppB);
    }
}

extern "C" void kernel_launch(void* const* d_in, const int* in_sizes, int n_in,
                              void* d_out, int out_size, void* d_ws, size_t ws_size,
                              hipStream_t stream) {
    const float* xyz    = (const float*)d_in[0];
    const float* nxyz   = (const float*)d_in[1];
    const float* points = (const float*)d_in[2];
    const float* npts   = (const float*)d_in[3];
    const float* Wk     = (const float*)d_in[4];
    const float* Wv     = (const float*)d_in[5];
    const float* Wp     = (const float*)d_in[6];
    // d_in[7] = bp — unused: constant-in-s logit shift cancels in softmax
    float* out = (float*)d_out;
    float* ws = (float*)d_ws;   // [65536][68] fp32 = 17.8 MB, fully rewritten each call

    hipLaunchKernelGGL(qkpp_kernel,     dim3(1024), dim3(256), 0, stream,
                       points, Wk, Wp, ws);
    hipLaunchKernelGGL(attn_out_kernel, dim3(512),  dim3(256), 0, stream,
                       xyz, nxyz, npts, Wv, ws, out);
}

// Round 12
// 115.361 us; speedup vs baseline: 1.1226x; 1.1226x over previous
//
#include <hip/hip_runtime.h>
#include <math.h>

constexpr int Nn = 16384;
constexpr int ST = 68;                      // ws row stride (dwords): 64 qk + 4 pp
constexpr size_t NS = (size_t)Nn * 16;      // dwords per channel plane of npts
constexpr int GPB = 4;                      // 16-pt groups per persistent block

// ---- DPP helpers ----
template <int CTRL>
__device__ __forceinline__ float dpp_f(float x) {
    return __int_as_float(
        __builtin_amdgcn_update_dpp(0, __float_as_int(x), CTRL, 0xF, 0xF, false));
}
// quad (4-lane) butterflies: quad_perm [1,0,3,2]=0xB1, [2,3,0,1]=0x4E
__device__ __forceinline__ float qsum4(float v) {
    v += dpp_f<0xB1>(v);
    v += dpp_f<0x4E>(v);
    return v;
}
__device__ __forceinline__ float qmax4(float v) {
    v = fmaxf(v, dpp_f<0xB1>(v));
    v = fmaxf(v, dpp_f<0x4E>(v));
    return v;
}

// LDS-visibility barrier that does NOT drain vmcnt: prefetched global loads
// stay in flight across it (__syncthreads would add s_waitcnt vmcnt(0)).
#define BAR() do { asm volatile("s_waitcnt lgkmcnt(0)" ::: "memory"); \
    __builtin_amdgcn_s_barrier(); asm volatile("" ::: "memory"); } while (0)

// ================= Kernel A: qk = Wk^T (q*scale), pp = Wp^T qk =================
// thread = (point, 16-channel quarter); no LDS. (unchanged)
__global__ __launch_bounds__(256, 4) void qkpp_kernel(
    const float* __restrict__ points, const float* __restrict__ Wk,
    const float* __restrict__ Wp, float* __restrict__ ws)
{
    const int tid = threadIdx.x;
    const int lane = tid & 63;
    const int q = lane >> 4;                            // quarter 0..3
    const int pt = blockIdx.x * 64 + (tid >> 6) * 16 + (lane & 15);
    const int b = pt >> 14;
    const int n = pt & (Nn - 1);

    float qk[16];
#pragma unroll
    for (int k = 0; k < 16; ++k) qk[k] = 0.f;

    const float* prow = points + (size_t)b * 64 * Nn + n;
    const float* wkq = Wk + 16 * q;
#pragma unroll 4
    for (int c = 0; c < 64; ++c) {
        const float qv = prow[(size_t)c * Nn];
        const float4 w0 = *(const float4*)(wkq + c * 64 + 0);
        const float4 w1 = *(const float4*)(wkq + c * 64 + 4);
        const float4 w2 = *(const float4*)(wkq + c * 64 + 8);
        const float4 w3 = *(const float4*)(wkq + c * 64 + 12);
        qk[0]  = fmaf(qv, w0.x, qk[0]);  qk[1]  = fmaf(qv, w0.y, qk[1]);
        qk[2]  = fmaf(qv, w0.z, qk[2]);  qk[3]  = fmaf(qv, w0.w, qk[3]);
        qk[4]  = fmaf(qv, w1.x, qk[4]);  qk[5]  = fmaf(qv, w1.y, qk[5]);
        qk[6]  = fmaf(qv, w1.z, qk[6]);  qk[7]  = fmaf(qv, w1.w, qk[7]);
        qk[8]  = fmaf(qv, w2.x, qk[8]);  qk[9]  = fmaf(qv, w2.y, qk[9]);
        qk[10] = fmaf(qv, w2.z, qk[10]); qk[11] = fmaf(qv, w2.w, qk[11]);
        qk[12] = fmaf(qv, w3.x, qk[12]); qk[13] = fmaf(qv, w3.y, qk[13]);
        qk[14] = fmaf(qv, w3.z, qk[14]); qk[15] = fmaf(qv, w3.w, qk[15]);
    }
#pragma unroll
    for (int k = 0; k < 16; ++k) qk[k] *= 0.125f;       // fold SCALE

    float p0 = 0.f, p1 = 0.f, p2 = 0.f, p3 = 0.f;
#pragma unroll
    for (int k = 0; k < 16; ++k) {
        const float4 wp4 = *(const float4*)(Wp + (16 * q + k) * 4);
        p0 = fmaf(qk[k], wp4.x, p0);
        p1 = fmaf(qk[k], wp4.y, p1);
        p2 = fmaf(qk[k], wp4.z, p2);
        p3 = fmaf(qk[k], wp4.w, p3);
    }
    p0 += __shfl_xor(p0, 16); p0 += __shfl_xor(p0, 32);
    p1 += __shfl_xor(p1, 16); p1 += __shfl_xor(p1, 32);
    p2 += __shfl_xor(p2, 16); p2 += __shfl_xor(p2, 32);
    p3 += __shfl_xor(p3, 16); p3 += __shfl_xor(p3, 32);

    float* orow = ws + (size_t)pt * ST + 16 * q;
    ((float4*)orow)[0] = make_float4(qk[0],  qk[1],  qk[2],  qk[3]);
    ((float4*)orow)[1] = make_float4(qk[4],  qk[5],  qk[6],  qk[7]);
    ((float4*)orow)[2] = make_float4(qk[8],  qk[9],  qk[10], qk[11]);
    ((float4*)orow)[3] = make_float4(qk[12], qk[13], qk[14], qk[15]);
    if (q == 0)
        *(float4*)(ws + (size_t)pt * ST + 64) = make_float4(p0, p1, p2, p3);
}

// ====== Kernel B: R10 layout + liveness-based prefetch + lgkm-only barriers ======
// Persistent block of 4 waves handles GPB=4 groups of 16 points. Wave w owns
// channels 16w..16w+15; lane l: point p=l>>2, s-quad sq=l&3. Next group's
// loads are issued into the SAME registers right after their last use (vbar),
// so HBM latency hides under the matvec phase; barriers never drain vmcnt.
__global__ __launch_bounds__(256, 3) void attn_out_kernel(
    const float* __restrict__ xyz, const float* __restrict__ nxyz,
    const float* __restrict__ npts, const float* __restrict__ Wv,
    const float* __restrict__ ws, float* __restrict__ out)
{
    __shared__ float wvT[67 * 68];                     // [c][o], stride 68
    __shared__ __align__(16) float lexch[4][64][4];    // partial-logit exchange
    __shared__ float vbexch[67 * 17];                  // vbar exchange, stride 17

    const int tid = threadIdx.x;
    const int w = tid >> 6;
    const int l = tid & 63;
    const int p = l >> 2;
    const int sq = l & 3;
    const int gptbase = blockIdx.x * (16 * GPB);       // 64-pt chunk, never straddles b
    const int b = gptbase >> 14;
    const int ngbase = gptbase & (Nn - 1);

    // one-time Wv transpose stage; visibility covered by the first in-loop BAR
    for (int idx = tid; idx < 64 * 67; idx += 256) {
        const int o = idx / 67, c = idx - o * 67;
        wvT[c * 68 + o] = Wv[idx];
    }

    const float* npb0 = npts + ((size_t)(b * 64 + 16 * w)) * NS + (size_t)ngbase * 16 + 4 * l;

    float4 npv4[16], qq[4], nx[3], pp = make_float4(0, 0, 0, 0);
    float xx[3] = {0, 0, 0};
    nx[0] = nx[1] = nx[2] = make_float4(0, 0, 0, 0);

    // ---- prologue: load group 0 ----
    {
#pragma unroll
        for (int k = 0; k < 16; ++k) npv4[k] = *(const float4*)(npb0 + (size_t)k * NS);
        const float* qrow = ws + (size_t)(gptbase + p) * ST + 16 * w;
        qq[0] = ((const float4*)qrow)[0];
        qq[1] = ((const float4*)qrow)[1];
        qq[2] = ((const float4*)qrow)[2];
        qq[3] = ((const float4*)qrow)[3];
        if (w == 3) {
            nx[0] = *(const float4*)(nxyz + ((size_t)(b * 3 + 0) * Nn + ngbase) * 16 + 4 * l);
            nx[1] = *(const float4*)(nxyz + ((size_t)(b * 3 + 1) * Nn + ngbase) * 16 + 4 * l);
            nx[2] = *(const float4*)(nxyz + ((size_t)(b * 3 + 2) * Nn + ngbase) * 16 + 4 * l);
            xx[0] = xyz[(size_t)(b * 3 + 0) * Nn + ngbase + p];
            xx[1] = xyz[(size_t)(b * 3 + 1) * Nn + ngbase + p];
            xx[2] = xyz[(size_t)(b * 3 + 2) * Nn + ngbase + p];
            pp = *(const float4*)(ws + (size_t)(gptbase + p) * ST + 64);
        }
    }

#pragma unroll
    for (int g = 0; g < GPB; ++g) {
        const int ng = ngbase + 16 * g;

        // relative position (w==3 only); nx/xx die here
        float4 d04 = make_float4(0, 0, 0, 0), d14 = d04, d24 = d04, dn4 = d04;
        if (w == 3) {
            d04 = make_float4(xx[0] - nx[0].x, xx[0] - nx[0].y, xx[0] - nx[0].z, xx[0] - nx[0].w);
            d14 = make_float4(xx[1] - nx[1].x, xx[1] - nx[1].y, xx[1] - nx[1].z, xx[1] - nx[1].w);
            d24 = make_float4(xx[2] - nx[2].x, xx[2] - nx[2].y, xx[2] - nx[2].z, xx[2] - nx[2].w);
            dn4 = make_float4(sqrtf(d04.x * d04.x + d14.x * d14.x + d24.x * d24.x),
                              sqrtf(d04.y * d04.y + d14.y * d14.y + d24.y * d24.y),
                              sqrtf(d04.z * d04.z + d14.z * d14.z + d24.z * d24.z),
                              sqrtf(d04.w * d04.w + d14.w * d14.w + d24.w * d24.w));
        }

        // partial logit over own 16 channels; qq dies here
        const float qks[16] = {qq[0].x, qq[0].y, qq[0].z, qq[0].w,
                               qq[1].x, qq[1].y, qq[1].z, qq[1].w,
                               qq[2].x, qq[2].y, qq[2].z, qq[2].w,
                               qq[3].x, qq[3].y, qq[3].z, qq[3].w};
        float4 lp = make_float4(0.f, 0.f, 0.f, 0.f);
#pragma unroll
        for (int k = 0; k < 16; ++k) {
            lp.x = fmaf(qks[k], npv4[k].x, lp.x);
            lp.y = fmaf(qks[k], npv4[k].y, lp.y);
            lp.z = fmaf(qks[k], npv4[k].z, lp.z);
            lp.w = fmaf(qks[k], npv4[k].w, lp.w);
        }
        if (w == 3) {   // + pp . pos  (bp const in s -> cancels in softmax)
            lp.x += pp.x * d04.x + pp.y * d14.x + pp.z * d24.x + pp.w * dn4.x;
            lp.y += pp.x * d04.y + pp.y * d14.y + pp.z * d24.y + pp.w * dn4.y;
            lp.z += pp.x * d04.z + pp.y * d14.z + pp.z * d24.z + pp.w * dn4.z;
            lp.w += pp.x * d04.w + pp.y * d14.w + pp.z * d24.w + pp.w * dn4.w;
        }

        BAR();                                  // WAR: prev group's lexch reads done
        *(float4*)&lexch[w][l][0] = lp;
        BAR();                                  // lexch visible
        const float4 g0 = *(const float4*)&lexch[0][l][0];
        const float4 g1 = *(const float4*)&lexch[1][l][0];
        const float4 g2 = *(const float4*)&lexch[2][l][0];
        const float4 g3 = *(const float4*)&lexch[3][l][0];
        const float4 lg = make_float4(g0.x + g1.x + g2.x + g3.x,
                                      g0.y + g1.y + g2.y + g3.y,
                                      g0.z + g1.z + g2.z + g3.z,
                                      g0.w + g1.w + g2.w + g3.w);

        // softmax over 16 s: in-lane(4) + quad reduce, pure DPP
        float mx = fmaxf(fmaxf(lg.x, lg.y), fmaxf(lg.z, lg.w));
        mx = qmax4(mx);
        const float e0 = __expf(lg.x - mx), e1 = __expf(lg.y - mx);
        const float e2 = __expf(lg.z - mx), e3 = __expf(lg.w - mx);
        const float se = qsum4((e0 + e1) + (e2 + e3));
        const float inv = 1.0f / se;
        const float at0 = e0 * inv, at1 = e1 * inv, at2 = e2 * inv, at3 = e3 * inv;

        // vbar over own channels -> LDS exchange; npv4 dies here
#pragma unroll
        for (int k = 0; k < 16; ++k) {
            float v = at0 * npv4[k].x + at1 * npv4[k].y + at2 * npv4[k].z + at3 * npv4[k].w;
            v = qsum4(v);                       // vbar[16w+k][p] in all 4 quad lanes
            if (sq == (k & 3)) vbexch[(16 * w + k) * 17 + p] = v;
        }
        if (w == 3) {                           // tail channels 64..66 (= tmp); d dies here
            const float t0 = qsum4(at0 * d04.x + at1 * d04.y + at2 * d04.z + at3 * d04.w);
            const float t1 = qsum4(at0 * d14.x + at1 * d14.y + at2 * d14.z + at3 * d14.w);
            const float t2 = qsum4(at0 * d24.x + at1 * d24.y + at2 * d24.z + at3 * d24.w);
            if (sq == 0) vbexch[64 * 17 + p] = t0;
            else if (sq == 1) vbexch[65 * 17 + p] = t1;
            else if (sq == 2) vbexch[66 * 17 + p] = t2;
        }

        // ---- prefetch group g+1 into the now-dead registers; the loads stay
        //      in flight across the next BAR (lgkm-only) and land under matvec ----
        if (g + 1 < GPB) {
            const float* npb = npb0 + (size_t)(g + 1) * 256;
#pragma unroll
            for (int k = 0; k < 16; ++k) npv4[k] = *(const float4*)(npb + (size_t)k * NS);
            const float* qrow = ws + (size_t)(gptbase + 16 * (g + 1) + p) * ST + 16 * w;
            qq[0] = ((const float4*)qrow)[0];
            qq[1] = ((const float4*)qrow)[1];
            qq[2] = ((const float4*)qrow)[2];
            qq[3] = ((const float4*)qrow)[3];
            if (w == 3) {
                const int ng2 = ngbase + 16 * (g + 1);
                nx[0] = *(const float4*)(nxyz + ((size_t)(b * 3 + 0) * Nn + ng2) * 16 + 4 * l);
                nx[1] = *(const float4*)(nxyz + ((size_t)(b * 3 + 1) * Nn + ng2) * 16 + 4 * l);
                nx[2] = *(const float4*)(nxyz + ((size_t)(b * 3 + 2) * Nn + ng2) * 16 + 4 * l);
                xx[0] = xyz[(size_t)(b * 3 + 0) * Nn + ng2 + p];
                xx[1] = xyz[(size_t)(b * 3 + 1) * Nn + ng2 + p];
                xx[2] = xyz[(size_t)(b * 3 + 2) * Nn + ng2 + p];
                pp = *(const float4*)(ws + (size_t)(gptbase + 16 * (g + 1) + p) * ST + 64);
            }
        }

        BAR();                                  // vbexch visible (no vmcnt drain)

        // out matvec: wave w covers o = 16w..16w+15; lane -> o-quad 16w+4sq
        float4 oa = make_float4(0.f, 0.f, 0.f, 0.f);
#pragma unroll
        for (int c = 0; c < 67; ++c) {
            const float vb = vbexch[c * 17 + p];
            const float4 wq = *(const float4*)&wvT[c * 68 + 16 * w + 4 * sq];
            oa.x = fmaf(vb, wq.x, oa.x);
            oa.y = fmaf(vb, wq.y, oa.y);
            oa.z = fmaf(vb, wq.z, oa.z);
            oa.w = fmaf(vb, wq.w, oa.w);
        }

        float* ob = out + ((size_t)(b * 64 + 16 * w + 4 * sq)) * Nn + ng + p;
        ob[0]              = oa.x;
        ob[(size_t)Nn]     = oa.y;
        ob[(size_t)Nn * 2] = oa.z;
        ob[(size_t)Nn * 3] = oa.w;
    }
}

extern "C" void kernel_launch(void* const* d_in, const int* in_sizes, int n_in,
                              void* d_out, int out_size, void* d_ws, size_t ws_size,
                              hipStream_t stream) {
    const float* xyz    = (const float*)d_in[0];
    const float* nxyz   = (const float*)d_in[1];
    const float* points = (const float*)d_in[2];
    const float* npts   = (const float*)d_in[3];
    const float* Wk     = (const float*)d_in[4];
    const float* Wv     = (const float*)d_in[5];
    const float* Wp     = (const float*)d_in[6];
    // d_in[7] = bp — unused: constant-in-s logit shift cancels in softmax
    float* out = (float*)d_out;
    float* ws = (float*)d_ws;   // [65536][68] fp32 = 17.8 MB, fully rewritten each call

    hipLaunchKernelGGL(qkpp_kernel,     dim3(1024), dim3(256), 0, stream,
                       points, Wk, Wp, ws);
    hipLaunchKernelGGL(attn_out_kernel, dim3(1024), dim3(256), 0, stream,
                       xyz, nxyz, npts, Wv, ws, out);
}